// Round 1
// baseline (358.433 us; speedup 1.0000x reference)
//
#include <hip/hip_runtime.h>
#include <cstdint>
#include <cstddef>

// ---------------------------------------------------------------------------
// SpatialGRU 32x32, B=64, U=64, C=64. Persistent: 32 rows x 4 batch-tiles.
// R7: latency-path restructure.
//  - hbuf layout changed to [b][u] f16 (LSB=1 validity per half): consumer
//    waves load their MFMA hT fragments DIRECTLY from hbuf (8 dwords/lane),
//    removing the hT LDS staging + the barrier between poll and GEMM1.
//  - GEMM1 split: k=64:256 (hL/hD/s, locally known) runs BEFORE the poll
//    completes; only k=0:64 (2 MFMAs) remains after hT arrives.
//  - softmax moved off the [F] tail into [E] on idle waves 0..3 (writes
//    zpart/eiinv in-place into Gsz); [F] tail = tanh + fma + store -> the
//    cross-row store issues earlier (smaller c_v).
//  - r-gating multiply moved into [E]: waves 0..2 store r (f16) only; waves
//    4..6 form (r*h) fragments from rf x qs32. Wave 7 stages hT->qs32.
// Still 3 barriers/iteration; LDS unchanged at 61952 B.
// ---------------------------------------------------------------------------

#define LDIM   32
#define BATCH  64
#define UNITS  64
#define CHAN   64
#define NBT    4
#define BT     16
#define TPB    512

typedef _Float16 f16;
typedef _Float16 f16x8 __attribute__((ext_vector_type(8)));
typedef float    f32x4 __attribute__((ext_vector_type(4)));
typedef uint32_t u32x4 __attribute__((ext_vector_type(4)));

__global__ __launch_bounds__(TPB, 2) void spatial_gru_kernel(
    const float* __restrict__ x,     // (B, C, 32, 32)
    const float* __restrict__ W,     // (256, 448)
    const float* __restrict__ Urec,  // (192, 64)
    const float* __restrict__ bias,  // (512,)
    const float* __restrict__ Wij,   // (64, 64)
    float* __restrict__ out,         // (B, U)
    uint32_t* __restrict__ hbuf)     // (32,32,NBT) slots of 512 dw = f16[16][64]
{
    const int bid = blockIdx.x;
    const int row = bid >> 2;
    const int bt  = bid & 3;
    const int b0  = bt * BT;
    const int t   = (int)threadIdx.x;
    const int u   = t & 63;
    const int g   = t >> 6;          // wave id 0..7
    const int l15 = t & 15;          // MFMA n-col / A-row lane
    const int lq  = (t & 63) >> 4;   // MFMA k-quad

    // ---- LDS ----
    // qf  : GEMM A staging (f16) [b][k]  k: 64:128 hL | 128:192 hD | 192:256 s
    // rf  : r gates (f16, NOT r*h)       [b][0:192]
    // qs32: fp32 state [b][c]  c: 0:64 hT | 64:128 hL | 128:192 hD
    // Gsz : z logits fp32 [b][0:256]; after [E]: [b][u]=zpart, [b][64+u]=eiinv
    // pacc: GEMM2 partials [w][b][n]
    __shared__ __attribute__((aligned(16))) f16 qf[BT][264];
    __shared__ __attribute__((aligned(16))) f16 rf[BT][200];
    __shared__ float qs32[BT][204];
    __shared__ float Gsz [BT][260];
    __shared__ float pacc[4][BT][68];

    // ---- GEMM1 weights resident (waves 0..6: 64 n-cols each) ----
    f16x8 wreg[4][8];
    float bias1[4] = {0.f, 0.f, 0.f, 0.f};
    if (g < 7) {
        const int nb = g * 64 + l15;
#pragma unroll
        for (int T = 0; T < 4; ++T) {
            bias1[T] = bias[nb + 16 * T];
#pragma unroll
            for (int s = 0; s < 8; ++s) {
                f16x8 v;
#pragma unroll
                for (int jj = 0; jj < 8; ++jj) {
                    int kk = s * 32 + lq * 8 + jj;
                    v[jj] = (f16)W[(size_t)kk * 448 + nb + 16 * T];
                }
                wreg[T][s] = v;
            }
        }
    }
    // ---- GEMM2 weights: wave g>=4 holds k-chunk [(g&3)*64, +64) of [Urec;Wij]
    f16x8 wreg2[4][2];
    if (g >= 4) {
        const int kb = (g & 3) * 64;
#pragma unroll
        for (int T = 0; T < 4; ++T) {
            const int nn = T * 16 + l15;
#pragma unroll
            for (int s = 0; s < 2; ++s) {
                f16x8 v;
#pragma unroll
                for (int jj = 0; jj < 8; ++jj) {
                    int kk = kb + s * 32 + lq * 8 + jj;
                    float wv = (kk < 192) ? Urec[kk * 64 + nn] : Wij[(kk - 192) * 64 + nn];
                    v[jj] = (f16)wv;
                }
                wreg2[T][s] = v;
            }
        }
    }
    const float bij = bias[448 + u];

    // ---- zero initial hL/hD (hT is re-staged every iteration by wave 7) ----
    for (int idx = t; idx < 128 * BT; idx += TPB) {
        int b = idx & 15, k = 64 + (idx >> 4);
        qs32[b][k] = 0.f;
        qf[b][k] = (f16)0.f;
    }

    // x: this thread handles channel u, batches b0+g and b0+g+8
    const size_t xb0 = (size_t)(b0 + g) * 65536 + (size_t)u * 1024 + (size_t)row * 32;
    const size_t xb1 = xb0 + (size_t)8 * 65536;
    {   // stage x(j=0)
        float x0 = x[xb0], x1 = x[xb1];
        qf[g][192 + u]     = (f16)x0;
        qf[g + 8][192 + u] = (f16)x1;
    }

    for (int j = 0; j < LDIM; ++j) {
        __syncthreads();   // s1 — rotation + x staging (prev tail) visible

        // ---- [A] issue hT poll loads in MFMA-fragment layout ----
        // frag s=0: b=l15, u=lq*8..+7 -> dwords base+0..3
        // frag s=1: b=l15, u=32+lq*8..+7 -> dwords base+16..19
        uint32_t d0=0,d1=0,d2=0,d3=0,d4=0,d5=0,d6=0,d7=0;
        const uint32_t* sp = hbuf;
        if (row > 0) {
            sp = hbuf + ((((size_t)(row - 1) * LDIM + j) * NBT + bt) << 9)
                      + (l15 * 32 + lq * 4);
            d0 = __hip_atomic_load(sp + 0,  __ATOMIC_RELAXED, __HIP_MEMORY_SCOPE_AGENT);
            d1 = __hip_atomic_load(sp + 1,  __ATOMIC_RELAXED, __HIP_MEMORY_SCOPE_AGENT);
            d2 = __hip_atomic_load(sp + 2,  __ATOMIC_RELAXED, __HIP_MEMORY_SCOPE_AGENT);
            d3 = __hip_atomic_load(sp + 3,  __ATOMIC_RELAXED, __HIP_MEMORY_SCOPE_AGENT);
            d4 = __hip_atomic_load(sp + 16, __ATOMIC_RELAXED, __HIP_MEMORY_SCOPE_AGENT);
            d5 = __hip_atomic_load(sp + 17, __ATOMIC_RELAXED, __HIP_MEMORY_SCOPE_AGENT);
            d6 = __hip_atomic_load(sp + 18, __ATOMIC_RELAXED, __HIP_MEMORY_SCOPE_AGENT);
            d7 = __hip_atomic_load(sp + 19, __ATOMIC_RELAXED, __HIP_MEMORY_SCOPE_AGENT);
        }
        float nx0 = 0.f, nx1 = 0.f;
        if (j < LDIM - 1) { nx0 = x[xb0 + j + 1]; nx1 = x[xb1 + j + 1]; }

        // ---- [C-pre] GEMM1 k=64:256 (waves 0..6) — overlaps in-flight poll.
        //      wave 7: GEMM2 s-chunk (k=192:256) -> pacc[3] ----
        f32x4 acc[4];
        if (g < 7) {
#pragma unroll
            for (int T = 0; T < 4; ++T)
                acc[T] = (f32x4){bias1[T], bias1[T], bias1[T], bias1[T]};
#pragma unroll
            for (int s = 2; s < 8; ++s) {
                f16x8 a = *(const f16x8*)&qf[l15][s * 32 + lq * 8];
#pragma unroll
                for (int T = 0; T < 4; ++T)
                    acc[T] = __builtin_amdgcn_mfma_f32_16x16x32_f16(a, wreg[T][s], acc[T], 0, 0, 0);
            }
        } else {
            f32x4 a2[4];
#pragma unroll
            for (int T = 0; T < 4; ++T) a2[T] = (f32x4){0.f, 0.f, 0.f, 0.f};
#pragma unroll
            for (int s = 0; s < 2; ++s) {
                f16x8 a = *(const f16x8*)&qf[l15][192 + s * 32 + lq * 8];
#pragma unroll
                for (int T = 0; T < 4; ++T)
                    a2[T] = __builtin_amdgcn_mfma_f32_16x16x32_f16(a, wreg2[T][s], a2[T], 0, 0, 0);
            }
#pragma unroll
            for (int T = 0; T < 4; ++T)
#pragma unroll
                for (int r = 0; r < 4; ++r)
                    pacc[3][lq * 4 + r][T * 16 + l15] = a2[T][r];
        }

        // ---- complete poll: all 16 halves must carry LSB=1 (ws poison 0xAA fails) ----
        f16x8 ha0, ha1;
#pragma unroll
        for (int jj = 0; jj < 8; ++jj) { ha0[jj] = (f16)0.f; ha1[jj] = (f16)0.f; }
        if (row > 0) {
            while (((d0 & d1 & d2 & d3 & d4 & d5 & d6 & d7) & 0x00010001u) != 0x00010001u) {
                __builtin_amdgcn_s_sleep(1);
                d0 = __hip_atomic_load(sp + 0,  __ATOMIC_RELAXED, __HIP_MEMORY_SCOPE_AGENT);
                d1 = __hip_atomic_load(sp + 1,  __ATOMIC_RELAXED, __HIP_MEMORY_SCOPE_AGENT);
                d2 = __hip_atomic_load(sp + 2,  __ATOMIC_RELAXED, __HIP_MEMORY_SCOPE_AGENT);
                d3 = __hip_atomic_load(sp + 3,  __ATOMIC_RELAXED, __HIP_MEMORY_SCOPE_AGENT);
                d4 = __hip_atomic_load(sp + 16, __ATOMIC_RELAXED, __HIP_MEMORY_SCOPE_AGENT);
                d5 = __hip_atomic_load(sp + 17, __ATOMIC_RELAXED, __HIP_MEMORY_SCOPE_AGENT);
                d6 = __hip_atomic_load(sp + 18, __ATOMIC_RELAXED, __HIP_MEMORY_SCOPE_AGENT);
                d7 = __hip_atomic_load(sp + 19, __ATOMIC_RELAXED, __HIP_MEMORY_SCOPE_AGENT);
            }
            ha0 = __builtin_bit_cast(f16x8, (u32x4){d0, d1, d2, d3});
            ha1 = __builtin_bit_cast(f16x8, (u32x4){d4, d5, d6, d7});
        }

        // ---- [C-post] k=0:64 (2 MFMAs) + r-sigmoid / z-logit stores.
        //      wave 7: stage hT -> qs32 (f32) for [E]/softmax/[F] ----
        if (g < 7) {
#pragma unroll
            for (int T = 0; T < 4; ++T)
                acc[T] = __builtin_amdgcn_mfma_f32_16x16x32_f16(ha0, wreg[T][0], acc[T], 0, 0, 0);
#pragma unroll
            for (int T = 0; T < 4; ++T)
                acc[T] = __builtin_amdgcn_mfma_f32_16x16x32_f16(ha1, wreg[T][1], acc[T], 0, 0, 0);
            if (g < 3) {
#pragma unroll
                for (int T = 0; T < 4; ++T)
#pragma unroll
                    for (int r = 0; r < 4; ++r) {
                        float rr = 1.f / (1.f + __expf(-acc[T][r]));
                        rf[lq * 4 + r][g * 64 + T * 16 + l15] = (f16)rr;
                    }
            } else {
                const int zb = (g - 3) * 64;
#pragma unroll
                for (int T = 0; T < 4; ++T)
#pragma unroll
                    for (int r = 0; r < 4; ++r)
                        Gsz[lq * 4 + r][zb + T * 16 + l15] = acc[T][r];
            }
        } else {
#pragma unroll
            for (int jj = 0; jj < 8; ++jj) {
                qs32[l15][lq * 8 + jj]      = (float)ha0[jj];
                qs32[l15][32 + lq * 8 + jj] = (float)ha1[jj];
            }
        }
        __syncthreads();   // s2 — rf, Gsz, qs32-hT, pacc[3] ready

        // ---- [E] waves 4..6: GEMM2 r-chunks, fragments formed as r*h.
        //      waves 0..3: softmax partials in-place into Gsz ----
        if (g >= 4 && g < 7) {
            const int w  = g - 4;
            const int kb = w * 64;
            const int hb = (w == 0) ? 64 : (w == 1) ? 0 : 128;  // hL / hT / hD
            f32x4 a2[4];
#pragma unroll
            for (int T = 0; T < 4; ++T) a2[T] = (f32x4){0.f, 0.f, 0.f, 0.f};
#pragma unroll
            for (int s = 0; s < 2; ++s) {
                f16x8 a;
#pragma unroll
                for (int jj = 0; jj < 8; ++jj) {
                    int kk = s * 32 + lq * 8 + jj;
                    a[jj] = (f16)((float)rf[l15][kb + kk] * qs32[l15][hb + kk]);
                }
#pragma unroll
                for (int T = 0; T < 4; ++T)
                    a2[T] = __builtin_amdgcn_mfma_f32_16x16x32_f16(a, wreg2[T][s], a2[T], 0, 0, 0);
            }
#pragma unroll
            for (int T = 0; T < 4; ++T)
#pragma unroll
                for (int r = 0; r < 4; ++r)
                    pacc[w][lq * 4 + r][T * 16 + l15] = a2[T][r];
        } else if (g < 4) {
#pragma unroll
            for (int i = 0; i < 4; ++i) {
                const int b = g * 4 + i;
                float zi = Gsz[b][u],       zl = Gsz[b][64 + u];
                float zt = Gsz[b][128 + u], zd = Gsz[b][192 + u];
                float hT = qs32[b][u], hL = qs32[b][64 + u], hD = qs32[b][128 + u];
                float mx = fmaxf(fmaxf(zi, zl), fmaxf(zt, zd));
                float ei = __expf(zi - mx), el = __expf(zl - mx);
                float et = __expf(zt - mx), ed = __expf(zd - mx);
                float inv = 1.f / (ei + el + et + ed);
                Gsz[b][u]      = (el * hL + et * hT + ed * hD) * inv;  // zpart
                Gsz[b][64 + u] = ei * inv;                             // eiinv
            }
        }
        __syncthreads();   // s3 — pacc + zpart/eiinv ready

        // ---- [F] short tail: tanh + fma; EARLY packed store; rotate ----
        float hvv[2], hTv[2];
#pragma unroll
        for (int i = 0; i < 2; ++i) {
            const int b = g + 8 * i;
            float hh = bij + pacc[0][b][u] + pacc[1][b][u] + pacc[2][b][u] + pacc[3][b][u];
            float e2 = __expf(2.f * hh);
            float th = 1.f - 2.f / (e2 + 1.f);          // tanh
            hvv[i] = Gsz[b][u] + Gsz[b][64 + u] * th;
            hTv[i] = qs32[b][u];
        }
        {   // handoff: f16[b][u] halfword stores, LSB=1 validity
            uint16_t* hp = (uint16_t*)(hbuf + ((((size_t)row * LDIM + j) * NBT + bt) << 9));
            uint16_t v0 = (uint16_t)(__builtin_bit_cast(uint16_t, (f16)hvv[0]) | 1u);
            uint16_t v1 = (uint16_t)(__builtin_bit_cast(uint16_t, (f16)hvv[1]) | 1u);
            __hip_atomic_store(hp + (g * 64 + u),       v0, __ATOMIC_RELAXED, __HIP_MEMORY_SCOPE_AGENT);
            __hip_atomic_store(hp + ((g + 8) * 64 + u), v1, __ATOMIC_RELAXED, __HIP_MEMORY_SCOPE_AGENT);
        }
        if (row == LDIM - 1 && j == LDIM - 1) {
            out[(size_t)(b0 + g) * UNITS + u]     = hvv[0];
            out[(size_t)(b0 + g + 8) * UNITS + u] = hvv[1];
        }
        // rotations (thread-own slots): hD <- hT, hL <- h_new; stage next x
#pragma unroll
        for (int i = 0; i < 2; ++i) {
            const int b = g + 8 * i;
            qs32[b][128 + u] = hTv[i];
            qs32[b][64 + u]  = hvv[i];
            qf[b][128 + u] = (f16)hTv[i];
            qf[b][64 + u]  = (f16)hvv[i];
        }
        qf[g][192 + u]     = (f16)nx0;
        qf[g + 8][192 + u] = (f16)nx1;
        // next s1 covers cross-wave visibility of all rotation writes
    }
}

extern "C" void kernel_launch(void* const* d_in, const int* in_sizes, int n_in,
                              void* d_out, int out_size, void* d_ws, size_t ws_size,
                              hipStream_t stream) {
    const float* x    = (const float*)d_in[0];
    const float* W    = (const float*)d_in[1];
    const float* Urec = (const float*)d_in[2];
    const float* bias = (const float*)d_in[3];
    const float* Wij  = (const float*)d_in[4];
    float* out = (float*)d_out;

    // hbuf: 32*32*4 slots x 512 dwords (f16[16][64] each) = 8 MB. Harness
    // re-poisons ws with 0xAA each launch; 0xAAAA halfwords fail the LSB test.
    uint32_t* hbuf = (uint32_t*)d_ws;

    spatial_gru_kernel<<<LDIM * NBT, TPB, 0, stream>>>(
        x, W, Urec, bias, Wij, out, hbuf);
}

// Round 2
// 259.385 us; speedup vs baseline: 1.3819x; 1.3819x over previous
//
#include <hip/hip_runtime.h>
#include <cstdint>
#include <cstddef>

// ---------------------------------------------------------------------------
// SpatialGRU 32x32, B=64, U=64, C=64. Persistent: 32 rows x 4 batch-tiles.
// R8 = R6 poll (1 own dword/thread, LDS-staged hT) + targeted latency cuts:
//  - GEMM1 split: poll load issued first; k=64:256 (hL/hD/s, locally known)
//    runs while the poll flies; only k=0:64 (2 MFMAs) is post-detect.
//    Costs one extra barrier (s1b) -> 4 barriers/iter.
//  - softmax moved off the [F] tail into [E] on idle waves 0..3 (writes
//    zpart/eiinv in place into Gsz); [F] tail = sum+tanh+fma+store.
//  - r*h stays in [C-post] (waves 0..2) as in R6 -> [E] keeps vector reads.
//  - XCD-affinity swizzle: p%8 -> row-group, so 24/31 vertical handoffs
//    stay on one XCD (dispatch round-robins XCDs by physical block id).
// hbuf: R6 layout — one dword per (g,u): 2xf16 packed, LSB=1 validity
// (harness ws poison 0xAA can never satisfy both LSBs).
// ---------------------------------------------------------------------------

#define LDIM   32
#define BATCH  64
#define UNITS  64
#define CHAN   64
#define NBT    4
#define BT     16
#define TPB    512

typedef _Float16 f16;
typedef _Float16 f16x8 __attribute__((ext_vector_type(8)));
typedef float    f32x4 __attribute__((ext_vector_type(4)));

__global__ __launch_bounds__(TPB, 2) void spatial_gru_kernel(
    const float* __restrict__ x,     // (B, C, 32, 32)
    const float* __restrict__ W,     // (256, 448)
    const float* __restrict__ Urec,  // (192, 64)
    const float* __restrict__ bias,  // (512,)
    const float* __restrict__ Wij,   // (64, 64)
    float* __restrict__ out,         // (B, U)
    uint32_t* __restrict__ hbuf)     // (32, 32, NBT, 512) packed 2xf16|LSB
{
    // XCD-affinity swizzle: physical block p lands on XCD p%8 (round-robin
    // dispatch). Give each XCD 4 consecutive rows x 4 bt, so vertical
    // handoffs r->r+1 stay on-XCD for r%4 != 3. Bijective on [0,128).
    const int p    = blockIdx.x;
    const int xcd  = p & 7;
    const int slot = p >> 3;         // 0..15
    const int row  = xcd * 4 + (slot >> 2);
    const int bt   = slot & 3;
    const int b0   = bt * BT;
    const int t    = (int)threadIdx.x;
    const int u    = t & 63;
    const int g    = t >> 6;         // wave id 0..7; also batch base
    const int l15  = t & 15;         // MFMA n-col / A-row lane
    const int lq   = (t & 63) >> 4;  // MFMA k-quad

    // ---- LDS ----
    // qf  : GEMM1 A (f16)  [b][k]  k: 0:64 hT | 64:128 hL | 128:192 hD | 192:256 s
    // rf  : GEMM2 A (f16)  [b][k]  k: 0:192 r*{hL,hT,hD}
    // qs32: fp32 state     [b][c]  c: 0:64 hT | 64:128 hL | 128:192 hD
    // Gsz : z logits fp32  [b][0:256]; after [E]: [b][u]=zpart, [b][64+u]=eiinv
    // pacc: GEMM2 partials [w][b][n]
    __shared__ __attribute__((aligned(16))) f16 qf[BT][264];
    __shared__ __attribute__((aligned(16))) f16 rf[BT][200];
    __shared__ float qs32[BT][204];
    __shared__ float Gsz [BT][260];
    __shared__ float pacc[4][BT][68];

    // ---- GEMM1 weights resident in registers (waves 0..6: 64 cols each) ----
    f16x8 wreg[4][8];
    float bias1[4] = {0.f, 0.f, 0.f, 0.f};
    if (g < 7) {
        const int nb = g * 64 + l15;
#pragma unroll
        for (int T = 0; T < 4; ++T) {
            bias1[T] = bias[nb + 16 * T];
#pragma unroll
            for (int s = 0; s < 8; ++s) {
                f16x8 v;
#pragma unroll
                for (int jj = 0; jj < 8; ++jj) {
                    int kk = s * 32 + lq * 8 + jj;
                    v[jj] = (f16)W[(size_t)kk * 448 + nb + 16 * T];
                }
                wreg[T][s] = v;
            }
        }
    }
    // ---- GEMM2 weights: wave g holds k-chunk [(g&3)*64, +64) of [Urec;Wij]
    //      (waves 4,5,6 -> r-chunks k=0,64,128; wave 7 -> s-chunk k=192) ----
    f16x8 wreg2[4][2];
    {
        const int kb = (g & 3) * 64;
#pragma unroll
        for (int T = 0; T < 4; ++T) {
            const int nn = T * 16 + l15;
#pragma unroll
            for (int s = 0; s < 2; ++s) {
                f16x8 v;
#pragma unroll
                for (int jj = 0; jj < 8; ++jj) {
                    int kk = kb + s * 32 + lq * 8 + jj;
                    float wv = (kk < 192) ? Urec[kk * 64 + nn] : Wij[(kk - 192) * 64 + nn];
                    v[jj] = (f16)wv;
                }
                wreg2[T][s] = v;
            }
        }
    }
    const float bij = bias[448 + u];

    // ---- zero initial state (hT/hL/hD = 0) ----
    for (int idx = t; idx < 192 * BT; idx += TPB) {
        int b = idx & 15, k = idx >> 4;
        qs32[b][k] = 0.f;
        qf[b][k] = (f16)0.f;
    }

    // x: this thread handles channel u, batches b0+g and b0+g+8
    const size_t xb0 = (size_t)(b0 + g) * 65536 + (size_t)u * 1024 + (size_t)row * 32;
    const size_t xb1 = xb0 + (size_t)8 * 65536;
    {   // stage x(j=0)
        float x0 = x[xb0], x1 = x[xb1];
        qf[g][192 + u]     = (f16)x0;
        qf[g + 8][192 + u] = (f16)x1;
    }

    for (int j = 0; j < LDIM; ++j) {
        __syncthreads();   // s1 — prev-tail rotation + x staging (and init) visible

        // ---- [A] issue own-dword poll load (flies during [C-pre]) ----
        uint32_t w = 0;
        const uint32_t* sp = hbuf;
        if (row > 0) {
            sp = hbuf + ((((size_t)(row - 1) * LDIM + j) * NBT + bt) << 9) + (g << 6) + u;
            w = __hip_atomic_load(sp, __ATOMIC_RELAXED, __HIP_MEMORY_SCOPE_AGENT);
        }
        // prefetch next cell's x (consumed at end of [F])
        float nx0 = 0.f, nx1 = 0.f;
        if (j < LDIM - 1) { nx0 = x[xb0 + j + 1]; nx1 = x[xb1 + j + 1]; }

        // ---- [C-pre] GEMM1 k=64:256 (waves 0..6; hL/hD/s all local).
        //      wave 7: GEMM2 s-chunk (k=192:256) -> pacc[3] ----
        f32x4 acc[4];
        if (g < 7) {
#pragma unroll
            for (int T = 0; T < 4; ++T)
                acc[T] = (f32x4){bias1[T], bias1[T], bias1[T], bias1[T]};
#pragma unroll
            for (int s = 2; s < 8; ++s) {
                f16x8 a = *(const f16x8*)&qf[l15][s * 32 + lq * 8];
#pragma unroll
                for (int T = 0; T < 4; ++T)
                    acc[T] = __builtin_amdgcn_mfma_f32_16x16x32_f16(a, wreg[T][s], acc[T], 0, 0, 0);
            }
        } else {
            f32x4 a2[4];
#pragma unroll
            for (int T = 0; T < 4; ++T) a2[T] = (f32x4){0.f, 0.f, 0.f, 0.f};
#pragma unroll
            for (int s = 0; s < 2; ++s) {
                f16x8 a = *(const f16x8*)&qf[l15][192 + s * 32 + lq * 8];
#pragma unroll
                for (int T = 0; T < 4; ++T)
                    a2[T] = __builtin_amdgcn_mfma_f32_16x16x32_f16(a, wreg2[T][s], a2[T], 0, 0, 0);
            }
#pragma unroll
            for (int T = 0; T < 4; ++T)
#pragma unroll
                for (int r = 0; r < 4; ++r)
                    pacc[3][lq * 4 + r][T * 16 + l15] = a2[T][r];
        }

        // ---- [A'] complete poll; unpack + stage hT (thread-own slots) ----
        {
            float ht0 = 0.f, ht1 = 0.f;
            f16 hf0 = (f16)0.f, hf1 = (f16)0.f;
            if (row > 0) {
                while ((w & 0x00010001u) != 0x00010001u) {
                    __builtin_amdgcn_s_sleep(1);
                    w = __hip_atomic_load(sp, __ATOMIC_RELAXED, __HIP_MEMORY_SCOPE_AGENT);
                }
                uint16_t lo = (uint16_t)(w & 0xFFFFu), hi = (uint16_t)(w >> 16);
                hf0 = __builtin_bit_cast(f16, lo);
                hf1 = __builtin_bit_cast(f16, hi);
                ht0 = (float)hf0;
                ht1 = (float)hf1;
            }
            qs32[g][u]     = ht0;  qf[g][u]     = hf0;
            qs32[g + 8][u] = ht1;  qf[g + 8][u] = hf1;
        }
        __syncthreads();   // s1b — hT staged visible

        // ---- [C-post] GEMM1 k=0:64 (2 MFMAs) + fused sigmoid (waves 0..2,
        //      writing rf = r*h as in R6) / z-logit stores (waves 3..6) ----
        if (g < 7) {
            {
                f16x8 a0 = *(const f16x8*)&qf[l15][lq * 8];
                f16x8 a1 = *(const f16x8*)&qf[l15][32 + lq * 8];
#pragma unroll
                for (int T = 0; T < 4; ++T)
                    acc[T] = __builtin_amdgcn_mfma_f32_16x16x32_f16(a0, wreg[T][0], acc[T], 0, 0, 0);
#pragma unroll
                for (int T = 0; T < 4; ++T)
                    acc[T] = __builtin_amdgcn_mfma_f32_16x16x32_f16(a1, wreg[T][1], acc[T], 0, 0, 0);
            }
            if (g < 3) {
                // g=0: r*hL (qs32 col 64+.), g=1: r*hT (col .), g=2: r*hD (col 128+.)
                const int colbase = (g == 0) ? 64 : (g == 1) ? 0 : 128;
#pragma unroll
                for (int T = 0; T < 4; ++T)
#pragma unroll
                    for (int r = 0; r < 4; ++r) {
                        float rr = 1.f / (1.f + __expf(-acc[T][r]));
                        int b = lq * 4 + r;
                        float hv = qs32[b][colbase + T * 16 + l15];
                        rf[b][g * 64 + T * 16 + l15] = (f16)(rr * hv);
                    }
            } else {
                const int zb = (g - 3) * 64;
#pragma unroll
                for (int T = 0; T < 4; ++T)
#pragma unroll
                    for (int r = 0; r < 4; ++r)
                        Gsz[lq * 4 + r][zb + T * 16 + l15] = acc[T][r];
            }
        }
        __syncthreads();   // s2 — rf + Gsz (+ pacc[3]) ready

        // ---- [E] waves 4..6: GEMM2 r-chunks (vector rf reads, private pacc).
        //      waves 0..3: softmax partials in place into Gsz ----
        if (g >= 4 && g < 7) {
            const int wv = g - 4;
            const int kb = wv * 64;
            f32x4 a2[4];
#pragma unroll
            for (int T = 0; T < 4; ++T) a2[T] = (f32x4){0.f, 0.f, 0.f, 0.f};
#pragma unroll
            for (int s = 0; s < 2; ++s) {
                f16x8 a = *(const f16x8*)&rf[l15][kb + s * 32 + lq * 8];
#pragma unroll
                for (int T = 0; T < 4; ++T)
                    a2[T] = __builtin_amdgcn_mfma_f32_16x16x32_f16(a, wreg2[T][s], a2[T], 0, 0, 0);
            }
#pragma unroll
            for (int T = 0; T < 4; ++T)
#pragma unroll
                for (int r = 0; r < 4; ++r)
                    pacc[wv][lq * 4 + r][T * 16 + l15] = a2[T][r];
        } else if (g < 4) {
#pragma unroll
            for (int i = 0; i < 4; ++i) {
                const int b = g * 4 + i;
                float zi = Gsz[b][u],       zl = Gsz[b][64 + u];
                float zt = Gsz[b][128 + u], zd = Gsz[b][192 + u];
                float hT = qs32[b][u], hL = qs32[b][64 + u], hD = qs32[b][128 + u];
                float mx = fmaxf(fmaxf(zi, zl), fmaxf(zt, zd));
                float ei = __expf(zi - mx), el = __expf(zl - mx);
                float et = __expf(zt - mx), ed = __expf(zd - mx);
                float inv = 1.f / (ei + el + et + ed);
                Gsz[b][u]      = (el * hL + et * hT + ed * hD) * inv;  // zpart
                Gsz[b][64 + u] = ei * inv;                             // eiinv
            }
        }
        __syncthreads();   // s3 — pacc + zpart/eiinv ready

        // ---- [F] short tail: sum + tanh + fma; EARLY packed store; rotate ----
        float hvv[2], hTv[2];
#pragma unroll
        for (int i = 0; i < 2; ++i) {
            const int b = g + 8 * i;
            float hh = bij + pacc[0][b][u] + pacc[1][b][u] + pacc[2][b][u] + pacc[3][b][u];
            float e2 = __expf(2.f * hh);
            float th = 1.f - 2.f / (e2 + 1.f);          // tanh
            hvv[i] = Gsz[b][u] + Gsz[b][64 + u] * th;
            hTv[i] = qs32[b][u];
        }
        {   // handoff: pack 2xf16 with LSB=1 validity, single agent store
            uint16_t lo = (uint16_t)(__builtin_bit_cast(uint16_t, (f16)hvv[0]) | 1u);
            uint16_t hi = (uint16_t)(__builtin_bit_cast(uint16_t, (f16)hvv[1]) | 1u);
            uint32_t pw = ((uint32_t)hi << 16) | lo;
            __hip_atomic_store(
                hbuf + ((((size_t)row * LDIM + j) * NBT + bt) << 9) + (g << 6) + u,
                pw, __ATOMIC_RELAXED, __HIP_MEMORY_SCOPE_AGENT);
        }
        if (row == LDIM - 1 && j == LDIM - 1) {
            out[(size_t)(b0 + g) * UNITS + u]     = hvv[0];
            out[(size_t)(b0 + g + 8) * UNITS + u] = hvv[1];
        }
        // rotations (thread-own slots): hD <- hT, hL <- h_new; stage next x
#pragma unroll
        for (int i = 0; i < 2; ++i) {
            const int b = g + 8 * i;
            qs32[b][128 + u] = hTv[i];
            qs32[b][64 + u]  = hvv[i];
            qf[b][128 + u] = (f16)hTv[i];
            qf[b][64 + u]  = (f16)hvv[i];
        }
        qf[g][192 + u]     = (f16)nx0;
        qf[g + 8][192 + u] = (f16)nx1;
        // next s1 (loop top) covers cross-wave visibility of rotation writes
    }
}

extern "C" void kernel_launch(void* const* d_in, const int* in_sizes, int n_in,
                              void* d_out, int out_size, void* d_ws, size_t ws_size,
                              hipStream_t stream) {
    const float* x    = (const float*)d_in[0];
    const float* W    = (const float*)d_in[1];
    const float* Urec = (const float*)d_in[2];
    const float* bias = (const float*)d_in[3];
    const float* Wij  = (const float*)d_in[4];
    float* out = (float*)d_out;

    // hbuf: 32*32*4*512 dwords = 8 MB. Harness re-poisons ws with 0xAA each
    // launch; 0xAAAAAAAA fails the (w & 0x10001)==0x10001 validity test.
    uint32_t* hbuf = (uint32_t*)d_ws;

    spatial_gru_kernel<<<LDIM * NBT, TPB, 0, stream>>>(
        x, W, Urec, bias, Wij, out, hbuf);
}